// Round 8
// baseline (181.183 us; speedup 1.0000x reference)
//
#include <hip/hip_runtime.h>

// ---------------------------------------------------------------------------
// MultiHeadAttentionLayer, MI355X (gfx950) — fused attention+projection
//
// Exact f32 rearrangement:
//   score_l = w . k_lh        w = (q_h^T A + g)/8,  A = Wq^T Wk, g = Wk^T bq
//             (per-(q,h) constants are softmax-invariant; bk drops)
//   vbar_h  = sum_l softmax(score)_l * v_lh   (sum p = 1 folds bv into b2)
//   out     = vbar @ Wo2B^T + b2              Wo2B[j][i] = sum_d Wo[j][h(i)*64+d]*Wv[d][i&63]
//
// softmax max-subtraction dropped: scores = w.k' with std ~0.2; overflow
// needs |score|>88 — >100 sigma. Math identical.
//
// R8: R7 was latency-starved (VALUBusy 4.7%, VGPR 40 -> loads serialized).
//   - Wm LDS staging dropped (L1 broadcast; saves 16.7 KB LDS + 1 barrier)
//   - phase A: 2 positions batched, 16 float4 loads pinned before math via
//     sched_barrier(0); two independent reduce chains interleave
//   - phase B: 16 v float4 loads pinned before FMA block (16 KB/wave in flight)
// ---------------------------------------------------------------------------

#define NFEAT 512
#define NHEAD 8
#define DHEAD 64
#define LWIN  16
#define WPOS  8           // bt per w_prepass block
#define FBT   16          // bt per attn_fused block (= MFMA M)
#define VPITCH 520        // vbar LDS pitch in bf16: 1040 B -> 16B-aligned rows

typedef __attribute__((ext_vector_type(8))) short bf16x8;
typedef __attribute__((ext_vector_type(4))) float f32x4;

__device__ __forceinline__ unsigned short f2bf(float f) {   // round-to-nearest-even
    unsigned int u = __float_as_uint(f);
    unsigned int r = (u + 0x7fffu + ((u >> 16) & 1u)) >> 16;
    return (unsigned short)r;
}

// ---- precompute A (64x64), g (64), b2 (512) -------------------------------
__global__ void precompute_small(const float* __restrict__ Wq, const float* __restrict__ bq,
                                 const float* __restrict__ Wk,
                                 const float* __restrict__ Wo, const float* __restrict__ bo,
                                 const float* __restrict__ bv,
                                 float* __restrict__ A, float* __restrict__ g,
                                 float* __restrict__ b2) {
    int idx = blockIdx.x * 256 + threadIdx.x;
    if (idx < 4096) {
        int d = idx >> 6, dp = idx & 63;
        float s = 0.f;
        #pragma unroll 8
        for (int e = 0; e < 64; ++e) s = fmaf(Wq[e * 64 + d], Wk[e * 64 + dp], s);
        A[idx] = s;
    } else if (idx < 4160) {
        int dp = idx - 4096;
        float s = 0.f;
        #pragma unroll 8
        for (int e = 0; e < 64; ++e) s = fmaf(Wk[e * 64 + dp], bq[e], s);
        g[dp] = s;
    } else if (idx < 4672) {
        int j = idx - 4160;
        float s = bo[j];
        #pragma unroll 8
        for (int i = 0; i < 512; ++i) s = fmaf(Wo[j * 512 + i], bv[i & 63], s);
        b2[j] = s;
    }
}

// ---- precompute Wo2B bf16 [j][i]: sum_d Wo[j][(i>>6)*64+d] * Wv[d][i&63] --
__global__ void precompute_wo2(const float* __restrict__ Wo, const float* __restrict__ Wv,
                               unsigned short* __restrict__ Wo2B) {
    int idx = blockIdx.x * 256 + threadIdx.x;   // 262144
    int i = idx & 511, j = idx >> 9;
    int h = i >> 6, e = i & 63;
    float s = 0.f;
    #pragma unroll 8
    for (int d = 0; d < 64; ++d)
        s = fmaf(Wo[j * 512 + h * 64 + d], Wv[d * 64 + e], s);
    Wo2B[(size_t)j * 512 + i] = f2bf(s);
}

// ---- w_prepass: Wm[bt][fe] = (sum_d q[bt][h*64+d] * A[d][fe&63] + g[fe&63]) / 8
__global__ __launch_bounds__(512, 4)
void w_prepass(const float* __restrict__ q, const float* __restrict__ A,
               const float* __restrict__ g, float* __restrict__ Wm) {
    __shared__ float As[4096];
    __shared__ float qs[WPOS][NFEAT];
    const int tid = threadIdx.x;
    const int bt0 = blockIdx.x * WPOS;

    #pragma unroll
    for (int i = 0; i < 8; ++i) As[i * 512 + tid] = A[i * 512 + tid];
    #pragma unroll
    for (int r = 0; r < WPOS; ++r) qs[r][tid] = q[(size_t)(bt0 + r) * NFEAT + tid];
    __syncthreads();

    const int e  = tid & 63;
    const int hb = (tid >> 6) << 6;
    float acc[WPOS];
    const float ge = g[e];
    #pragma unroll
    for (int r = 0; r < WPOS; ++r) acc[r] = ge;

    #pragma unroll 4
    for (int dq = 0; dq < 16; ++dq) {
        const float a0 = As[(4 * dq + 0) * 64 + e];
        const float a1 = As[(4 * dq + 1) * 64 + e];
        const float a2 = As[(4 * dq + 2) * 64 + e];
        const float a3 = As[(4 * dq + 3) * 64 + e];
        #pragma unroll
        for (int r = 0; r < WPOS; ++r) {
            const float4 qv = *reinterpret_cast<const float4*>(&qs[r][hb + 4 * dq]);
            acc[r] = fmaf(qv.x, a0, acc[r]);
            acc[r] = fmaf(qv.y, a1, acc[r]);
            acc[r] = fmaf(qv.z, a2, acc[r]);
            acc[r] = fmaf(qv.w, a3, acc[r]);
        }
    }
    #pragma unroll
    for (int r = 0; r < WPOS; ++r)
        Wm[(size_t)(bt0 + r) * NFEAT + tid] = acc[r] * 0.125f;
}

__device__ __forceinline__ void dot4x4(const float4 w0, const float4 w1,
                                       const float4 w2, const float4 w3,
                                       const float4 k0, const float4 k1,
                                       const float4 k2, const float4 k3,
                                       float& outv) {
    float a0 = 0.f, a1 = 0.f, a2 = 0.f, a3 = 0.f;
    a0 = fmaf(w0.x, k0.x, a0); a1 = fmaf(w0.y, k0.y, a1);
    a2 = fmaf(w0.z, k0.z, a2); a3 = fmaf(w0.w, k0.w, a3);
    a0 = fmaf(w1.x, k1.x, a0); a1 = fmaf(w1.y, k1.y, a1);
    a2 = fmaf(w1.z, k1.z, a2); a3 = fmaf(w1.w, k1.w, a3);
    a0 = fmaf(w2.x, k2.x, a0); a1 = fmaf(w2.y, k2.y, a1);
    a2 = fmaf(w2.z, k2.z, a2); a3 = fmaf(w2.w, k2.w, a3);
    a0 = fmaf(w3.x, k3.x, a0); a1 = fmaf(w3.y, k3.y, a1);
    a2 = fmaf(w3.z, k3.z, a2); a3 = fmaf(w3.w, k3.w, a3);
    outv = (a0 + a1) + (a2 + a3);
}

// ---- attn_fused: scores + softmax + vbar + output projection --------------
__global__ __launch_bounds__(512, 4)
void attn_fused(const float* __restrict__ Wm, const float* __restrict__ k,
                const float* __restrict__ v, const unsigned short* __restrict__ Wo2B,
                const float* __restrict__ b2, float* __restrict__ out) {
    __shared__ float ps[NHEAD][FBT][17];                      // 8.7 KB
    __shared__ __align__(16) unsigned short vbarS[FBT * VPITCH];  // 16.6 KB

    const int tid = threadIdx.x;
    const int bt0 = blockIdx.x * FBT;

    // ---------------- phase A: scores + softmax (2 bt batched) -------------
    {
        const int h    = tid >> 6;
        const int lane = tid & 63;
        const int l    = lane >> 2;          // window slot 0..15
        const int d4   = lane & 3;           // 16-float d-chunk
        const int off  = h * 64 + d4 * 16;

        for (int pp2 = 0; pp2 < FBT / 2; ++pp2) {
            const int pa = 2 * pp2, pb = 2 * pp2 + 1;
            const float4* wA = reinterpret_cast<const float4*>(
                Wm + (size_t)(bt0 + pa) * NFEAT + off);
            const float4* wB = reinterpret_cast<const float4*>(
                Wm + (size_t)(bt0 + pb) * NFEAT + off);
            const float4* kA = reinterpret_cast<const float4*>(
                k + (size_t)(bt0 + pa) * (LWIN * NFEAT) + (size_t)l * NFEAT + off);
            const float4* kB = reinterpret_cast<const float4*>(
                k + (size_t)(bt0 + pb) * (LWIN * NFEAT) + (size_t)l * NFEAT + off);

            // ---- 16 loads issued before any math (pinned) ----
            const float4 wa0 = wA[0], wa1 = wA[1], wa2 = wA[2], wa3 = wA[3];
            const float4 ka0 = kA[0], ka1 = kA[1], ka2 = kA[2], ka3 = kA[3];
            const float4 wb0 = wB[0], wb1 = wB[1], wb2 = wB[2], wb3 = wB[3];
            const float4 kb0 = kB[0], kb1 = kB[1], kb2 = kB[2], kb3 = kB[3];
            __builtin_amdgcn_sched_barrier(0);

            float sa, sb;
            dot4x4(wa0, wa1, wa2, wa3, ka0, ka1, ka2, ka3, sa);
            dot4x4(wb0, wb1, wb2, wb3, kb0, kb1, kb2, kb3, sb);

            // two independent reduce chains, interleaved
            sa += __shfl_xor(sa, 1, 64);  sb += __shfl_xor(sb, 1, 64);
            sa += __shfl_xor(sa, 2, 64);  sb += __shfl_xor(sb, 2, 64);
            const float ea = __expf(sa);  const float eb = __expf(sb);
            float da = ea, db = eb;
            da += __shfl_xor(da, 4, 64);  db += __shfl_xor(db, 4, 64);
            da += __shfl_xor(da, 8, 64);  db += __shfl_xor(db, 8, 64);
            da += __shfl_xor(da, 16, 64); db += __shfl_xor(db, 16, 64);
            da += __shfl_xor(da, 32, 64); db += __shfl_xor(db, 32, 64);
            if (d4 == 0) {
                ps[h][pa][l] = ea * (1.0f / da);
                ps[h][pb][l] = eb * (1.0f / db);
            }
        }
    }
    __syncthreads();

    // ---------------- phase B: vbar = sum_l p_l * v_l -> bf16 LDS ----------
    {
        const int pq = tid >> 7;             // 0..3
        const int f4 = tid & 127;            // float4 chunk of 512 features
        const int hh = f4 >> 4;
        for (int ii = 0; ii < 4; ++ii) {
            const int bt = ii * 4 + pq;      // 0..15
            float pv[LWIN];
            #pragma unroll
            for (int i = 0; i < LWIN; ++i) pv[i] = ps[hh][bt][i];   // LDS bcast
            const float4* vp = reinterpret_cast<const float4*>(
                v + (size_t)(bt0 + bt) * (LWIN * NFEAT)) + f4;

            // ---- 16 independent loads issued before any FMA (pinned) ----
            const float4 x0  = vp[ 0 * 128], x1  = vp[ 1 * 128];
            const float4 x2  = vp[ 2 * 128], x3  = vp[ 3 * 128];
            const float4 x4  = vp[ 4 * 128], x5  = vp[ 5 * 128];
            const float4 x6  = vp[ 6 * 128], x7  = vp[ 7 * 128];
            const float4 x8  = vp[ 8 * 128], x9  = vp[ 9 * 128];
            const float4 x10 = vp[10 * 128], x11 = vp[11 * 128];
            const float4 x12 = vp[12 * 128], x13 = vp[13 * 128];
            const float4 x14 = vp[14 * 128], x15 = vp[15 * 128];
            __builtin_amdgcn_sched_barrier(0);

            float ax = 0.f, ay = 0.f, az = 0.f, aw = 0.f;
            ax = fmaf(pv[ 0], x0.x,  ax); ay = fmaf(pv[ 0], x0.y,  ay);
            az = fmaf(pv[ 0], x0.z,  az); aw = fmaf(pv[ 0], x0.w,  aw);
            ax = fmaf(pv[ 1], x1.x,  ax); ay = fmaf(pv[ 1], x1.y,  ay);
            az = fmaf(pv[ 1], x1.z,  az); aw = fmaf(pv[ 1], x1.w,  aw);
            ax = fmaf(pv[ 2], x2.x,  ax); ay = fmaf(pv[ 2], x2.y,  ay);
            az = fmaf(pv[ 2], x2.z,  az); aw = fmaf(pv[ 2], x2.w,  aw);
            ax = fmaf(pv[ 3], x3.x,  ax); ay = fmaf(pv[ 3], x3.y,  ay);
            az = fmaf(pv[ 3], x3.z,  az); aw = fmaf(pv[ 3], x3.w,  aw);
            ax = fmaf(pv[ 4], x4.x,  ax); ay = fmaf(pv[ 4], x4.y,  ay);
            az = fmaf(pv[ 4], x4.z,  az); aw = fmaf(pv[ 4], x4.w,  aw);
            ax = fmaf(pv[ 5], x5.x,  ax); ay = fmaf(pv[ 5], x5.y,  ay);
            az = fmaf(pv[ 5], x5.z,  az); aw = fmaf(pv[ 5], x5.w,  aw);
            ax = fmaf(pv[ 6], x6.x,  ax); ay = fmaf(pv[ 6], x6.y,  ay);
            az = fmaf(pv[ 6], x6.z,  az); aw = fmaf(pv[ 6], x6.w,  aw);
            ax = fmaf(pv[ 7], x7.x,  ax); ay = fmaf(pv[ 7], x7.y,  ay);
            az = fmaf(pv[ 7], x7.z,  az); aw = fmaf(pv[ 7], x7.w,  aw);
            ax = fmaf(pv[ 8], x8.x,  ax); ay = fmaf(pv[ 8], x8.y,  ay);
            az = fmaf(pv[ 8], x8.z,  az); aw = fmaf(pv[ 8], x8.w,  aw);
            ax = fmaf(pv[ 9], x9.x,  ax); ay = fmaf(pv[ 9], x9.y,  ay);
            az = fmaf(pv[ 9], x9.z,  az); aw = fmaf(pv[ 9], x9.w,  aw);
            ax = fmaf(pv[10], x10.x, ax); ay = fmaf(pv[10], x10.y, ay);
            az = fmaf(pv[10], x10.z, az); aw = fmaf(pv[10], x10.w, aw);
            ax = fmaf(pv[11], x11.x, ax); ay = fmaf(pv[11], x11.y, ay);
            az = fmaf(pv[11], x11.z, az); aw = fmaf(pv[11], x11.w, aw);
            ax = fmaf(pv[12], x12.x, ax); ay = fmaf(pv[12], x12.y, ay);
            az = fmaf(pv[12], x12.z, az); aw = fmaf(pv[12], x12.w, aw);
            ax = fmaf(pv[13], x13.x, ax); ay = fmaf(pv[13], x13.y, ay);
            az = fmaf(pv[13], x13.z, az); aw = fmaf(pv[13], x13.w, aw);
            ax = fmaf(pv[14], x14.x, ax); ay = fmaf(pv[14], x14.y, ay);
            az = fmaf(pv[14], x14.z, az); aw = fmaf(pv[14], x14.w, aw);
            ax = fmaf(pv[15], x15.x, ax); ay = fmaf(pv[15], x15.y, ay);
            az = fmaf(pv[15], x15.z, az); aw = fmaf(pv[15], x15.w, aw);

            unsigned short o[4] = { f2bf(ax), f2bf(ay), f2bf(az), f2bf(aw) };
            *reinterpret_cast<uint2*>(vbarS + bt * VPITCH + f4 * 4) =
                *reinterpret_cast<uint2*>(o);
        }
    }
    __syncthreads();

    // ---------------- phase C: out = vbar @ Wo2B^T + b2 (MFMA) -------------
    {
        const int w    = tid >> 6;           // wave -> n0
        const int lane = tid & 63;
        const int n0   = w * 64;
        const int r    = lane & 15;          // A row / B col / D col
        const int kg   = lane >> 4;          // k-group

        const unsigned short* As0 = vbarS + r * VPITCH + kg * 8;
        const short* Bb0 = (const short*)Wo2B + ((size_t)(n0 +  0 + r)) * 512 + kg * 8;
        const short* Bb1 = (const short*)Wo2B + ((size_t)(n0 + 16 + r)) * 512 + kg * 8;
        const short* Bb2 = (const short*)Wo2B + ((size_t)(n0 + 32 + r)) * 512 + kg * 8;
        const short* Bb3 = (const short*)Wo2B + ((size_t)(n0 + 48 + r)) * 512 + kg * 8;

        f32x4 acc0 = {0.f, 0.f, 0.f, 0.f}, acc1 = acc0, acc2 = acc0, acc3 = acc0;

        #pragma unroll 4
        for (int kk = 0; kk < 16; ++kk) {
            const bf16x8 a   = *reinterpret_cast<const bf16x8*>(As0 + kk * 32); // ds_read_b128
            const bf16x8 b0  = *reinterpret_cast<const bf16x8*>(Bb0 + kk * 32);
            const bf16x8 b1  = *reinterpret_cast<const bf16x8*>(Bb1 + kk * 32);
            const bf16x8 b2v = *reinterpret_cast<const bf16x8*>(Bb2 + kk * 32);
            const bf16x8 b3  = *reinterpret_cast<const bf16x8*>(Bb3 + kk * 32);
            acc0 = __builtin_amdgcn_mfma_f32_16x16x32_bf16(a, b0,  acc0, 0, 0, 0);
            acc1 = __builtin_amdgcn_mfma_f32_16x16x32_bf16(a, b1,  acc1, 0, 0, 0);
            acc2 = __builtin_amdgcn_mfma_f32_16x16x32_bf16(a, b2v, acc2, 0, 0, 0);
            acc3 = __builtin_amdgcn_mfma_f32_16x16x32_bf16(a, b3,  acc3, 0, 0, 0);
        }

        const float bb0 = b2[n0 + 0 + r],  bb1 = b2[n0 + 16 + r];
        const float bb2 = b2[n0 + 32 + r], bb3 = b2[n0 + 48 + r];
        #pragma unroll
        for (int j = 0; j < 4; ++j) {        // D: col = lane&15, row = kg*4+j
            const size_t row = (size_t)(bt0 + kg * 4 + j) * 512;
            out[row + n0 +  0 + r] = acc0[j] + bb0;
            out[row + n0 + 16 + r] = acc1[j] + bb1;
            out[row + n0 + 32 + r] = acc2[j] + bb2;
            out[row + n0 + 48 + r] = acc3[j] + bb3;
        }
    }
}

// ---------------------------------------------------------------------------
extern "C" void kernel_launch(void* const* d_in, const int* in_sizes, int n_in,
                              void* d_out, int out_size, void* d_ws, size_t ws_size,
                              hipStream_t stream) {
    const float* q  = (const float*)d_in[0];
    const float* k  = (const float*)d_in[1];
    const float* v  = (const float*)d_in[2];
    const float* Wq = (const float*)d_in[3];
    const float* bq = (const float*)d_in[4];
    const float* Wk = (const float*)d_in[5];
    // d_in[6] = bk: provably unused (softmax-invariant)
    const float* Wv = (const float*)d_in[7];
    const float* bv = (const float*)d_in[8];
    const float* Wo = (const float*)d_in[9];
    const float* bo = (const float*)d_in[10];
    float* out = (float*)d_out;

    float* ws = (float*)d_ws;
    float*          A    = ws;                         // 4096 f32
    float*          g    = ws + 4096;                  // 64
    float*          b2   = ws + 4160;                  // 512
    unsigned short* Wo2B = (unsigned short*)(ws + 4672);        // 256K bf16
    float*          Wm   = ws + 4672 + 131072;         // 4194304 f32 (16 MB)
    // total ws usage ~ 16.5 MB

    const int BT = in_sizes[0] / NFEAT;  // 8192

    hipLaunchKernelGGL(precompute_small, dim3(19), dim3(256), 0, stream,
                       Wq, bq, Wk, Wo, bo, bv, A, g, b2);
    hipLaunchKernelGGL(precompute_wo2, dim3(1024), dim3(256), 0, stream,
                       Wo, Wv, Wo2B);
    hipLaunchKernelGGL(w_prepass, dim3(BT / WPOS), dim3(512), 0, stream,
                       q, A, g, Wm);
    hipLaunchKernelGGL(attn_fused, dim3(BT / FBT), dim3(512), 0, stream,
                       Wm, k, v, Wo2B, b2, out);
}